// Round 3
// baseline (123.458 us; speedup 1.0000x reference)
//
#include <hip/hip_runtime.h>
#include <hip/hip_bf16.h>

// Capsule dynamic routing, factored to avoid materializing u_hat (268 MB).
// B=64 batches, N=2048 input capsules, D=64 in-dim, I=32 out capsules, J=16 out dim.
// Key identities:
//   o[b,i,:]  = (sum_n c[b,i,n] * u[b,n,:]) @ W_i          (t-then-W)
//   b[b,i,n]  = u[b,n,:] . (W_i @ o[b,i,:]) = u[b,n,:] . w~[b,i,:]
// so only u (33.5 MB) is streamed; per-iteration state is t/w~ (512 KB each).

#define BB 64
#define NN 2048
#define DD 64
#define II 32
#define JJ 16

// ---------------- kernel 1: s[b,d] = sum_n u[b,n,d] ----------------
__global__ __launch_bounds__(256) void ksum(const float* __restrict__ u,
                                            float* __restrict__ s) {
    int b = blockIdx.y;
    int chunk = blockIdx.x;                 // 0..7, 256 rows each
    int d = threadIdx.x & 63;
    int g = threadIdx.x >> 6;               // 0..3
    const float* ub = u + (size_t)b * NN * DD;
    float acc = 0.f;
    int n0 = chunk * 256;
    for (int n = n0 + g; n < n0 + 256; n += 4)
        acc += ub[(size_t)n * DD + d];      // coalesced: lanes d consecutive
    __shared__ float red[4][64];
    red[g][d] = acc;
    __syncthreads();
    if (g == 0) {
        float v = red[0][d] + red[1][d] + red[2][d] + red[3][d];
        atomicAdd(&s[b * DD + d], v);
    }
}

// ---------------- small kernel: per-(b,i) o, normalize, w~ (or squash->out) ----
// MODE 0: src = s[b][64], o = (1/32) s @ W_i, l2norm, write w~
// MODE 1: src = t[b][i][64], o = t @ W_i, l2norm, write w~
// MODE 2: src = t[b][i][64], o = t @ W_i, squash, write out
template <int MODE>
__global__ __launch_bounds__(512) void ksmall(const float* __restrict__ src,
                                              const float* __restrict__ W,
                                              float* __restrict__ w_out,
                                              float* __restrict__ out) {
    int b = blockIdx.x;
    int tid = threadIdx.x;                  // 512 = 32 capsules x 16 dims
    int i = tid >> 4;
    int j = tid & 15;
    const float* trow = (MODE == 0) ? (src + (size_t)b * DD)
                                    : (src + ((size_t)b * II + i) * DD);
    float o = 0.f;
    #pragma unroll 4
    for (int d = 0; d < DD; ++d)
        o += trow[d] * W[d * (II * JJ) + i * JJ + j];   // W col reads coalesced over tid
    if (MODE == 0) o *= (1.0f / 32.0f);

    // sum of squares over the 16 j-lanes (subgroups of 16 within the wave)
    float ss = o * o;
    #pragma unroll
    for (int off = 8; off >= 1; off >>= 1)
        ss += __shfl_xor(ss, off, 16);

    if (MODE == 2) {
        float s2 = ss + 1e-7f;                       // K.epsilon
        float scale = sqrtf(s2) / (0.5f + s2);       // squash
        out[((size_t)b * II + i) * JJ + j] = scale * o;
        return;
    }

    float norm = sqrtf(fmaxf(ss, 1e-12f));           // tf l2_normalize
    float ov = o / norm;
    __shared__ float osh[II][JJ];
    osh[i][j] = ov;
    __syncthreads();
    // w~[b][i][d] = sum_j W[d][i*16+j] * o[i][j]; thread covers d = j + 16k
    #pragma unroll
    for (int k = 0; k < 4; ++k) {
        int d = j + 16 * k;
        float acc = 0.f;
        #pragma unroll
        for (int jj = 0; jj < 16; ++jj)
            acc += W[d * (II * JJ) + i * JJ + jj] * osh[i][jj];
        w_out[((size_t)b * II + i) * DD + d] = acc;
    }
}

// ---------------- big kernel: one routing pass ----------------
// b[n,i] = u[n,:].w~[i,:]  -> softmax over i -> c; then t[i,d] += sum_n c[n,i] u[n,d]
__global__ __launch_bounds__(256) void kbig(const float* __restrict__ u,
                                            const float* __restrict__ w,
                                            float* __restrict__ t) {
    int b = blockIdx.y;
    int chunk = blockIdx.x;                 // 0..7, 256 rows each
    const float* ub = u + (size_t)b * NN * DD;
    const float* wb = w + (size_t)b * II * DD;

    __shared__ float wsh[II][DD];           // 8 KB
    __shared__ float csh[256][II + 1];      // 33 KB, padded (+1) for phase-1 writes
    int tid = threadIdx.x;

    for (int idx = tid; idx < II * DD; idx += 256)
        wsh[idx >> 6][idx & 63] = wb[idx];
    __syncthreads();

    // ---- phase 1: one thread per row n; 32 dots + in-register softmax ----
    int n = chunk * 256 + tid;
    const float* urow = ub + (size_t)n * DD;
    float bacc[II];
    #pragma unroll
    for (int i = 0; i < II; ++i) bacc[i] = 0.f;
    #pragma unroll 4
    for (int d0 = 0; d0 < DD; d0 += 4) {
        float4 u4 = *reinterpret_cast<const float4*>(urow + d0);
        #pragma unroll
        for (int i = 0; i < II; ++i) {
            float4 w4 = *reinterpret_cast<const float4*>(&wsh[i][d0]);  // broadcast
            bacc[i] += u4.x * w4.x + u4.y * w4.y + u4.z * w4.z + u4.w * w4.w;
        }
    }
    float m = bacc[0];
    #pragma unroll
    for (int i = 1; i < II; ++i) m = fmaxf(m, bacc[i]);
    float sum = 0.f;
    #pragma unroll
    for (int i = 0; i < II; ++i) { bacc[i] = __expf(bacc[i] - m); sum += bacc[i]; }
    float inv = 1.f / sum;
    #pragma unroll
    for (int i = 0; i < II; ++i) csh[tid][i] = bacc[i] * inv;
    __syncthreads();

    // ---- phase 2: t[i,d] partial = sum_n csh[n][i] * u[n][d] ----
    int d = tid & 63;
    int ib = tid >> 6;                      // wave id: i = ib + 4k, disjoint per wave
    float acc[8];
    #pragma unroll
    for (int k = 0; k < 8; ++k) acc[k] = 0.f;
    const float* ucol = ub + (size_t)(chunk * 256) * DD + d;
    for (int nn2 = 0; nn2 < 256; ++nn2) {
        float uv = ucol[(size_t)nn2 * DD];  // coalesced 256B/wave, L1/L2-hit
        #pragma unroll
        for (int k = 0; k < 8; ++k)
            acc[k] += csh[nn2][ib + 4 * k] * uv;   // LDS broadcast within wave
    }
    #pragma unroll
    for (int k = 0; k < 8; ++k)
        atomicAdd(&t[((size_t)b * II + ib + 4 * k) * DD + d], acc[k]);
}

extern "C" void kernel_launch(void* const* d_in, const int* in_sizes, int n_in,
                              void* d_out, int out_size, void* d_ws, size_t ws_size,
                              hipStream_t stream) {
    const float* u = (const float*)d_in[0];     // (64, 2048, 64)
    const float* W = (const float*)d_in[1];     // (1, 64, 512)
    float* out = (float*)d_out;                 // (64, 32, 16)
    float* ws = (float*)d_ws;

    float* s  = ws;                             // 4096 floats
    float* t1 = ws + 4096;                      // 131072 floats
    float* t2 = ws + 4096 + 131072;             // 131072 floats
    float* wv = ws + 4096 + 2 * 131072;         // 131072 floats (w~)

    // zero the atomically-accumulated buffers (harness does not re-poison)
    hipMemsetAsync(ws, 0, (4096 + 2 * 131072) * sizeof(float), stream);

    dim3 grid(8, BB);
    ksum<<<grid, 256, 0, stream>>>(u, s);
    ksmall<0><<<BB, 512, 0, stream>>>(s, W, wv, nullptr);   // iter0: uniform c
    kbig<<<grid, 256, 0, stream>>>(u, wv, t1);              // iter1 big pass
    ksmall<1><<<BB, 512, 0, stream>>>(t1, W, wv, nullptr);
    kbig<<<grid, 256, 0, stream>>>(u, wv, t2);              // iter2 big pass
    ksmall<2><<<BB, 512, 0, stream>>>(t2, W, nullptr, out); // squash -> out
}